// Round 9
// baseline (1308.107 us; speedup 1.0000x reference)
//
#include <hip/hip_runtime.h>
#include <hip/hip_bf16.h>
#include <hip/hip_fp16.h>

typedef unsigned short u16;
typedef __attribute__((ext_vector_type(8))) short short8;
typedef __attribute__((ext_vector_type(8))) _Float16 half8;
typedef __attribute__((ext_vector_type(4))) float floatx4;

__device__ __forceinline__ float bf2f(u16 u) {
    unsigned x = (unsigned)u << 16;
    return __uint_as_float(x);
}
__device__ __forceinline__ u16 f2bf(float f) {   // RNE
    unsigned x = __float_as_uint(f);
    unsigned r = (x + 0x7fffu + ((x >> 16) & 1u)) >> 16;
    return (u16)r;
}
__device__ __forceinline__ u16 f2h(float f) {
    __half h = __float2half(f);
    return __half_as_ushort(h);
}
__device__ __forceinline__ float h2f(u16 u) {
    return __half2float(__ushort_as_half(u));
}

__device__ __forceinline__ float wave_sum(float v) {
    #pragma unroll
    for (int off = 32; off; off >>= 1) v += __shfl_xor(v, off);
    return v;
}

// async global->LDS, 16B/lane; LDS base wave-uniform (HW adds lane*16)
__device__ __forceinline__ void async16(const u16* g, const u16* lds) {
    __builtin_amdgcn_global_load_lds(
        (const __attribute__((address_space(1))) void*)g,
        (__attribute__((address_space(3))) void*)lds, 16, 0, 0);
}

// ---------------------------------------------------------------------------
// Low-precision MFMA GEMM (DT=0 bf16, DT=1 fp16), z-batched.
// C = act(A @ B + bias); Bt = B^T [N][K]; A,Bt u16 payload of DT dtype.
// 128x128 tile / 256 threads / 4 waves; fp32 accumulate; async16 staging.
// transC: Cb written V-transposed Cb[((row>>10)*512+col)<<10 | (row&1023)].
// ---------------------------------------------------------------------------
template <int DT>
__global__ __launch_bounds__(256) void gemm_lp(
    const u16* __restrict__ A, int lda, long strideAz,
    const u16* __restrict__ Bt, int ldb, long strideBz,
    const float* __restrict__ bias, int strideBiasZ,
    float* __restrict__ Cf, u16* __restrict__ Cb, int ldc, long strideCz,
    int K, int act, int transC)
{
    __shared__ __align__(16) u16 Asm[128 * 32];
    __shared__ __align__(16) u16 Bsm[128 * 32];

    A += (size_t)blockIdx.z * strideAz;
    Bt += (size_t)blockIdx.z * strideBz;
    if (bias) bias += (size_t)blockIdx.z * strideBiasZ;
    if (Cf) Cf += (size_t)blockIdx.z * strideCz;
    if (Cb) Cb += (size_t)blockIdx.z * strideCz;

    const int tid = threadIdx.x;
    const int lane = tid & 63;
    const int wave = tid >> 6;
    const int m0 = blockIdx.y * 128, n0 = blockIdx.x * 128;
    const int wm = (wave >> 1) * 64, wn = (wave & 1) * 64;

    const int r0 = tid >> 2;
    const int kc = (tid & 3) * 8;
    const int kq = (lane >> 4) * 8;
    const int fm = lane & 15;

    const floatx4 zz = {0.f, 0.f, 0.f, 0.f};
    floatx4 acc[4][4];
    #pragma unroll
    for (int mt = 0; mt < 4; ++mt)
        #pragma unroll
        for (int nt = 0; nt < 4; ++nt) acc[mt][nt] = zz;

    const u16* ldsA0 = Asm + wave * 512;
    const u16* ldsA1 = Asm + 2048 + wave * 512;
    const u16* ldsB0 = Bsm + wave * 512;
    const u16* ldsB1 = Bsm + 2048 + wave * 512;

    for (int kt = 0; kt < K; kt += 32) {
        async16(&A[(size_t)(m0 + r0) * lda + kt + kc],      ldsA0);
        async16(&A[(size_t)(m0 + r0 + 64) * lda + kt + kc], ldsA1);
        async16(&Bt[(size_t)(n0 + r0) * ldb + kt + kc],      ldsB0);
        async16(&Bt[(size_t)(n0 + r0 + 64) * ldb + kt + kc], ldsB1);
        __syncthreads();

        #pragma unroll
        for (int mt = 0; mt < 4; ++mt) {
            #pragma unroll
            for (int nt = 0; nt < 4; ++nt) {
                if constexpr (DT == 0) {
                    short8 af = *(const short8*)&Asm[(wm + mt * 16 + fm) * 32 + kq];
                    short8 bf = *(const short8*)&Bsm[(wn + nt * 16 + fm) * 32 + kq];
                    acc[mt][nt] = __builtin_amdgcn_mfma_f32_16x16x32_bf16(af, bf, acc[mt][nt], 0, 0, 0);
                } else {
                    half8 af = *(const half8*)&Asm[(wm + mt * 16 + fm) * 32 + kq];
                    half8 bf = *(const half8*)&Bsm[(wn + nt * 16 + fm) * 32 + kq];
                    acc[mt][nt] = __builtin_amdgcn_mfma_f32_16x16x32_f16(af, bf, acc[mt][nt], 0, 0, 0);
                }
            }
        }
        __syncthreads();
    }

    const int cr = (lane >> 4) * 4;
    #pragma unroll
    for (int mt = 0; mt < 4; ++mt) {
        #pragma unroll
        for (int nt = 0; nt < 4; ++nt) {
            const int col = n0 + wn + nt * 16 + fm;
            const float bz = bias ? bias[col] : 0.f;
            #pragma unroll
            for (int r = 0; r < 4; ++r) {
                const int row = m0 + wm + mt * 16 + cr + r;
                float v = acc[mt][nt][r] + bz;
                if (act) v = fmaxf(v, 0.f);
                if (Cf) Cf[(size_t)row * ldc + col] = v;
                if (Cb) {
                    u16 ov = (DT == 0) ? f2bf(v) : f2h(v);
                    if (transC)
                        Cb[(((size_t)(row >> 10) * 512 + col) << 10) + (row & 1023)] = ov;
                    else
                        Cb[(size_t)row * ldc + col] = ov;
                }
            }
        }
    }
}

// ---------------------------------------------------------------------------
// fp32 [K][N] -> u16 [N][K] transposed (DT=0 bf16, DT=1 fp16), batched.
// ---------------------------------------------------------------------------
template <int DT>
__global__ __launch_bounds__(256) void tconv_kernel(
    const float* __restrict__ in, u16* __restrict__ out, int K, int N)
{
    __shared__ float t[32][33];
    const int n0 = blockIdx.x * 32, k0 = blockIdx.y * 32;
    const size_t bo = (size_t)blockIdx.z * K * N;
    const int tx = threadIdx.x & 31, ty = threadIdx.x >> 5;
    const float* src = in + bo;
    u16* dst = out + bo;
    #pragma unroll
    for (int r = ty; r < 32; r += 8) t[r][tx] = src[(size_t)(k0 + r) * N + n0 + tx];
    __syncthreads();
    #pragma unroll
    for (int r = ty; r < 32; r += 8) {
        float v = t[tx][r];
        dst[(size_t)(n0 + r) * K + k0 + tx] = (DT == 0) ? f2bf(v) : f2h(v);
    }
}

// fp32 -> fp16 elementwise
__global__ void f2h_kernel(const float* __restrict__ in, u16* __restrict__ out, int n)
{
    int i = blockIdx.x * 256 + threadIdx.x;
    if (i < n) out[i] = f2h(in[i]);
}

// ---------------------------------------------------------------------------
__global__ void pe_kernel(float* __restrict__ pe)
{
    int idx = blockIdx.x * 256 + threadIdx.x;
    int s = idx >> 9, d = idx & 511;
    float div = expf((float)(d & ~1) * (-9.210340371976184f / 512.0f));
    float ang = (float)s * div;
    pe[idx] = (d & 1) ? cosf(ang) : sinf(ang);
}

__global__ void y_kernel(const float* __restrict__ qa, const float* __restrict__ pe,
                         u16* __restrict__ yb)
{
    int idx = blockIdx.x * 256 + threadIdx.x;
    yb[idx] = f2bf(qa[idx] + pe[idx & 524287]);
}

// ---------------------------------------------------------------------------
// Gate from fp16-GEMM partials: s = relu(ps0+ps1+ab); logits; top-2 softmax.
// Flags rows with top2-top3 gap < TAU for exact fp32 fixup.
// ---------------------------------------------------------------------------
#define GATE_TAU 4e-3f
__global__ __launch_bounds__(64) void gate_kernel(
    const float* __restrict__ ps, const float* __restrict__ ab,
    const float* __restrict__ m_seq,
    const float* __restrict__ gw, const float* __restrict__ gb,
    float* __restrict__ gates, int* __restrict__ flags)
{
    const int r = blockIdx.x, t = threadIdx.x;
    float p0 = 0.f, p1 = 0.f, p2 = 0.f, p3 = 0.f;
    const float* s0 = ps + (size_t)r * 512;
    const float* s1 = ps + 2097152 + (size_t)r * 512;
    for (int j = t; j < 512; j += 64) {
        float s = fmaxf(s0[j] + s1[j] + ab[j], 0.f);
        const float* g = gw + (size_t)j * 4;
        p0 += s * g[0]; p1 += s * g[1]; p2 += s * g[2]; p3 += s * g[3];
    }
    {
        float m = m_seq[(size_t)r * 64 + t];
        const float* g = gw + (size_t)(512 + t) * 4;
        p0 += m * g[0]; p1 += m * g[1]; p2 += m * g[2]; p3 += m * g[3];
    }
    p0 = wave_sum(p0); p1 = wave_sum(p1); p2 = wave_sum(p2); p3 = wave_sum(p3);
    if (t == 0) {
        float lg[4] = { p0 + gb[0], p1 + gb[1], p2 + gb[2], p3 + gb[3] };
        float m1 = -INFINITY, m2 = -INFINITY, m3 = -INFINITY;
        #pragma unroll
        for (int k = 0; k < 4; ++k) {
            float v = lg[k];
            if (v > m1) { m3 = m2; m2 = m1; m1 = v; }
            else if (v > m2) { m3 = m2; m2 = v; }
            else if (v > m3) { m3 = v; }
        }
        flags[r] = (m2 - m3 < GATE_TAU) ? 1 : 0;
        float wv[4], s = 0.f;
        #pragma unroll
        for (int k = 0; k < 4; ++k) {
            wv[k] = (lg[k] >= m2) ? __expf(lg[k] - m1) : 0.f;
            s += wv[k];
        }
        float inv = 1.f / s;
        #pragma unroll
        for (int k = 0; k < 4; ++k) gates[(size_t)r * 4 + k] = wv[k] * inv;
    }
}

// ---------------------------------------------------------------------------
// Exact fp32 recompute of gate for flagged rows (top-k selection fidelity).
// One wave per row; early exit if unflagged.
// ---------------------------------------------------------------------------
__global__ __launch_bounds__(64) void fixup_kernel(
    const int* __restrict__ flags,
    const float* __restrict__ q_raw, const float* __restrict__ aw,
    const float* __restrict__ ab, const float* __restrict__ m_seq,
    const float* __restrict__ gw, const float* __restrict__ gb,
    float* __restrict__ gates)
{
    const int r = blockIdx.x;
    if (!flags[r]) return;
    const int t = threadIdx.x;
    const float* q = q_raw + (size_t)r * 3072;
    float s[8] = {};
    for (int k = 0; k < 3072; ++k) {
        const float qk = q[k];
        const float* w = aw + (size_t)k * 512 + t;
        #pragma unroll
        for (int c = 0; c < 8; ++c) s[c] += qk * w[c * 64];
    }
    float p0 = 0.f, p1 = 0.f, p2 = 0.f, p3 = 0.f;
    #pragma unroll
    for (int c = 0; c < 8; ++c) {
        const int j = t + c * 64;
        float sv = fmaxf(s[c] + ab[j], 0.f);
        const float* g = gw + (size_t)j * 4;
        p0 += sv * g[0]; p1 += sv * g[1]; p2 += sv * g[2]; p3 += sv * g[3];
    }
    {
        float m = m_seq[(size_t)r * 64 + t];
        const float* g = gw + (size_t)(512 + t) * 4;
        p0 += m * g[0]; p1 += m * g[1]; p2 += m * g[2]; p3 += m * g[3];
    }
    p0 = wave_sum(p0); p1 = wave_sum(p1); p2 = wave_sum(p2); p3 = wave_sum(p3);
    if (t == 0) {
        float lg[4] = { p0 + gb[0], p1 + gb[1], p2 + gb[2], p3 + gb[3] };
        float m1 = -INFINITY, m2 = -INFINITY;
        #pragma unroll
        for (int k = 0; k < 4; ++k) {
            float v = lg[k];
            if (v > m1) { m2 = m1; m1 = v; }
            else if (v > m2) { m2 = v; }
        }
        float wv[4], ssum = 0.f;
        #pragma unroll
        for (int k = 0; k < 4; ++k) {
            wv[k] = (lg[k] >= m2) ? __expf(lg[k] - m1) : 0.f;
            ssum += wv[k];
        }
        float inv = 1.f / ssum;
        #pragma unroll
        for (int k = 0; k < 4; ++k) gates[(size_t)r * 4 + k] = wv[k] * inv;
    }
}

// ---------------------------------------------------------------------------
__global__ __launch_bounds__(64) void moe_ln_kernel(
    const u16* __restrict__ experts, const float* __restrict__ gates,
    const float* __restrict__ g, const float* __restrict__ bb,
    const float* __restrict__ pe, float* __restrict__ x, u16* __restrict__ xb)
{
    const int r = blockIdx.x, t = threadIdx.x;
    const u16* e = experts + (size_t)r * 2048;
    const float g0 = gates[r * 4 + 0], g1 = gates[r * 4 + 1];
    const float g2 = gates[r * 4 + 2], g3 = gates[r * 4 + 3];
    float v[8];
    #pragma unroll
    for (int it = 0; it < 8; ++it) {
        int d = t + it * 64;
        v[it] = g0 * h2f(e[d]) + g1 * h2f(e[512 + d])
              + g2 * h2f(e[1024 + d]) + g3 * h2f(e[1536 + d]);
    }
    float s = 0.f;
    #pragma unroll
    for (int it = 0; it < 8; ++it) s += v[it];
    s = wave_sum(s);
    const float mu = s * (1.f / 512.f);
    float q = 0.f;
    #pragma unroll
    for (int it = 0; it < 8; ++it) { float dd = v[it] - mu; q += dd * dd; }
    q = wave_sum(q);
    const float rstd = rsqrtf(q * (1.f / 512.f) + 1e-5f);
    const float* per = pe + (size_t)(r & 1023) * 512;
    #pragma unroll
    for (int it = 0; it < 8; ++it) {
        int d = t + it * 64;
        float o = (v[it] - mu) * rstd * g[d] + bb[d] + per[d];
        x[(size_t)r * 512 + d] = o;
        xb[(size_t)r * 512 + d] = f2bf(o);
    }
}

// x = LN(x + t0 [+ t1] [+ bias])*g + b; writes x fp32, xb bf16, optional out2.
__global__ __launch_bounds__(64) void add_ln_kernel(
    float* __restrict__ x, u16* __restrict__ xb,
    const float* __restrict__ t0, const float* __restrict__ t1,
    const float* __restrict__ bias,
    const float* __restrict__ g, const float* __restrict__ bb,
    float* __restrict__ out2)
{
    const int r = blockIdx.x, t = threadIdx.x;
    float* xr = x + (size_t)r * 512;
    float v[8];
    #pragma unroll
    for (int it = 0; it < 8; ++it) {
        int d = t + it * 64;
        float tv = t0[(size_t)r * 512 + d];
        if (t1) tv += t1[(size_t)r * 512 + d];
        if (bias) tv += bias[d];
        v[it] = xr[d] + tv;
    }
    float s = 0.f;
    #pragma unroll
    for (int it = 0; it < 8; ++it) s += v[it];
    s = wave_sum(s);
    const float mu = s * (1.f / 512.f);
    float q = 0.f;
    #pragma unroll
    for (int it = 0; it < 8; ++it) { float dd = v[it] - mu; q += dd * dd; }
    q = wave_sum(q);
    const float rstd = rsqrtf(q * (1.f / 512.f) + 1e-5f);
    #pragma unroll
    for (int it = 0; it < 8; ++it) {
        int d = t + it * 64;
        float o = (v[it] - mu) * rstd * g[d] + bb[d];
        xr[d] = o;
        xb[(size_t)r * 512 + d] = f2bf(o);
        if (out2) out2[(size_t)r * 512 + d] = o;
    }
}

// ---------------------------------------------------------------------------
// MFMA flash strict-causal attention (bf16). V pre-transposed in global.
// ---------------------------------------------------------------------------
__global__ __launch_bounds__(256) void attn_kernel(
    const u16* __restrict__ kh, const u16* __restrict__ vhT,
    u16* __restrict__ ctx)
{
    __shared__ __align__(16) u16 Qs[64 * 64];
    __shared__ __align__(16) u16 Ks[64 * 64];
    __shared__ __align__(16) u16 Vt[64 * 72];
    __shared__ __align__(16) u16 Ps[64 * 72];

    const int tid = threadIdx.x;
    const int lane = tid & 63, wave = tid >> 6;
    const int quad = lane >> 4, fm = lane & 15;
    const int b = blockIdx.x, h = blockIdx.y;
    const int bz = blockIdx.z;
    const int it = (bz < 8) ? bz : (23 - bz);

    const u16* khb = kh + ((size_t)b * 1024) * 512 + h * 64;
    const u16* vtb = vhT + ((size_t)(b * 512 + h * 64)) * 1024;

    const int lj = tid >> 2;
    const int lc = tid & 3;

    {
        const u16* src = khb + (size_t)(it * 64 + lj) * 512 + lc * 16;
        *(uint4*)&Qs[lj * 64 + lc * 16]     = *(const uint4*)src;
        *(uint4*)&Qs[lj * 64 + lc * 16 + 8] = *(const uint4*)(src + 8);
    }

    const floatx4 zz = {0.f, 0.f, 0.f, 0.f};
    floatx4 o_acc[4];
    #pragma unroll
    for (int nt = 0; nt < 4; ++nt) o_acc[nt] = zz;
    float m_run[4] = { -INFINITY, -INFINITY, -INFINITY, -INFINITY };
    float l_run[4] = {};

    __syncthreads();

    for (int jt = 0; jt <= it; ++jt) {
        {
            const u16* ksrc = khb + (size_t)(jt * 64 + lj) * 512 + lc * 16;
            *(uint4*)&Ks[lj * 64 + lc * 16]     = *(const uint4*)ksrc;
            *(uint4*)&Ks[lj * 64 + lc * 16 + 8] = *(const uint4*)(ksrc + 8);
            const u16* vsrc = vtb + (size_t)lj * 1024 + jt * 64 + lc * 16;
            *(uint4*)&Vt[lj * 72 + lc * 16]     = *(const uint4*)vsrc;
            *(uint4*)&Vt[lj * 72 + lc * 16 + 8] = *(const uint4*)(vsrc + 8);
        }
        __syncthreads();

        floatx4 s_acc[4];
        #pragma unroll
        for (int nt = 0; nt < 4; ++nt) s_acc[nt] = zz;
        #pragma unroll
        for (int ks = 0; ks < 2; ++ks) {
            short8 af = *(const short8*)&Qs[(wave * 16 + fm) * 64 + ks * 32 + quad * 8];
            #pragma unroll
            for (int nt = 0; nt < 4; ++nt) {
                short8 bf = *(const short8*)&Ks[(nt * 16 + fm) * 64 + ks * 32 + quad * 8];
                s_acc[nt] = __builtin_amdgcn_mfma_f32_16x16x32_bf16(af, bf, s_acc[nt], 0, 0, 0);
            }
        }

        const bool diag = (jt == it);
        #pragma unroll
        for (int r = 0; r < 4; ++r) {
            const int rowi = wave * 16 + quad * 4 + r;
            float sv[4];
            #pragma unroll
            for (int nt = 0; nt < 4; ++nt) {
                float s = s_acc[nt][r] * 0.125f;
                if (diag && (nt * 16 + fm) >= rowi) s = -INFINITY;
                sv[nt] = s;
            }
            float mx = fmaxf(fmaxf(sv[0], sv[1]), fmaxf(sv[2], sv[3]));
            #pragma unroll
            for (int off = 1; off < 16; off <<= 1) mx = fmaxf(mx, __shfl_xor(mx, off));
            const float mn = fmaxf(m_run[r], mx);
            const float mfix = (mn == -INFINITY) ? 0.f : mn;
            const float alpha = (m_run[r] == -INFINITY) ? 0.f : __expf(m_run[r] - mn);
            m_run[r] = mn;
            float rs = 0.f;
            #pragma unroll
            for (int nt = 0; nt < 4; ++nt) {
                float p = __expf(sv[nt] - mfix);
                Ps[rowi * 72 + nt * 16 + fm] = f2bf(p);
                rs += p;
            }
            #pragma unroll
            for (int off = 1; off < 16; off <<= 1) rs += __shfl_xor(rs, off);
            l_run[r] = l_run[r] * alpha + rs;
            #pragma unroll
            for (int nt = 0; nt < 4; ++nt) o_acc[nt][r] *= alpha;
        }
        __syncthreads();

        #pragma unroll
        for (int ks = 0; ks < 2; ++ks) {
            short8 af = *(const short8*)&Ps[(wave * 16 + fm) * 72 + ks * 32 + quad * 8];
            #pragma unroll
            for (int nt = 0; nt < 4; ++nt) {
                short8 bf = *(const short8*)&Vt[(nt * 16 + fm) * 72 + ks * 32 + quad * 8];
                o_acc[nt] = __builtin_amdgcn_mfma_f32_16x16x32_bf16(af, bf, o_acc[nt], 0, 0, 0);
            }
        }
        __syncthreads();
    }

    u16* cb = ctx + ((size_t)b * 1024 + (size_t)it * 64 + wave * 16) * 512 + h * 64;
    #pragma unroll
    for (int r = 0; r < 4; ++r) {
        const int row = quad * 4 + r;
        const float inv = (l_run[r] > 0.f) ? 1.f / l_run[r] : 0.f;
        #pragma unroll
        for (int nt = 0; nt < 4; ++nt)
            cb[(size_t)row * 512 + nt * 16 + fm] = f2bf(o_acc[nt][r] * inv);
    }
}

// ---------------------------------------------------------------------------
extern "C" void kernel_launch(void* const* d_in, const int* in_sizes, int n_in,
                              void* d_out, int out_size, void* d_ws, size_t ws_size,
                              hipStream_t stream)
{
    const float* q_raw   = (const float*)d_in[0];
    const float* m_seq   = (const float*)d_in[1];
    const float* qa      = (const float*)d_in[2];
    const float* exp_w1  = (const float*)d_in[3];
    const float* exp_b1  = (const float*)d_in[4];
    const float* exp_w2  = (const float*)d_in[5];
    const float* exp_b2  = (const float*)d_in[6];
    const float* adapt_w = (const float*)d_in[7];
    const float* adapt_b = (const float*)d_in[8];
    const float* gate_w  = (const float*)d_in[9];
    const float* gate_b  = (const float*)d_in[10];
    const float* moe_g   = (const float*)d_in[11];
    const float* moe_b   = (const float*)d_in[12];
    const float* kw      = (const float*)d_in[13];
    const float* kb      = (const float*)d_in[14];
    const float* vw      = (const float*)d_in[15];
    const float* vb      = (const float*)d_in[16];
    const float* ow      = (const float*)d_in[17];
    const float* ob      = (const float*)d_in[18];
    const float* ln1g    = (const float*)d_in[19];
    const float* ln1b    = (const float*)d_in[20];
    const float* fw1     = (const float*)d_in[21];
    const float* fb1     = (const float*)d_in[22];
    const float* fw2     = (const float*)d_in[23];
    const float* fb2     = (const float*)d_in[24];
    const float* ln2g    = (const float*)d_in[25];
    const float* ln2b    = (const float*)d_in[26];
    float* out = (float*)d_out;

    const size_t NEED = 86048768ull;   // == round-2-proven workspace size
    if (ws_size < NEED) return;

    char* base = (char*)d_ws;
    float* x  = (float*)(base + 0);            // 8,388,608
    u16*  xb  = (u16*)(base + 8388608);        // 4,194,304
    u16*  yb  = (u16*)(base + 12582912);       // 4,194,304
    char* G = base + 16777216;                 // 69,271,552 budget
    // ---- MoE phase ----
    u16*   w1t    = (u16*)(G + 0);             //  4,718,592 fp16 [e][768][768]^T
    u16*   w2t    = (u16*)(G + 4718592);       //  3,145,728 fp16
    u16*   adaptt = (u16*)(G + 7864320);       //  3,145,728 fp16 [512][3072]
    u16*   q_h    = (u16*)(G + 11010048);      // 25,165,824 fp16 [4096][3072]
    float* psum   = (float*)(G + 36175872);    // 16,777,216 (2 x 4096x512 fp32)
    u16*   h1b2   = (u16*)(G + 36175872);      // 12,582,912 (2 experts; over dead psum)
    float* pe     = (float*)(G + 52953088);    //  2,097,152
    float* gates  = (float*)(G + 55050240);    //     65,536
    int*   flags  = (int*)(G + 55115776);      //     16,384
    u16*   expb   = (u16*)(G + 55132160);      //  8,388,608 fp16 [4096][4][512]
    // ---- layer phase (MoE buffers dead) ----
    u16*   kwt  = (u16*)(G + 0);               //  2,097,152 bf16
    u16*   vwt  = (u16*)(G + 2097152);
    u16*   owt  = (u16*)(G + 4194304);
    u16*   fw1t = (u16*)(G + 6291456);         //  8,388,608
    u16*   fw2t = (u16*)(G + 14680064);        //  8,388,608
    u16*   khb  = (u16*)(G + 23068672);        //  4,194,304
    u16*   vhT  = (u16*)(G + 27262976);
    u16*   ctxb = (u16*)(G + 31457280);
    float* p    = (float*)(G + 35651584);      //  8,388,608
    u16*   ffhb = (u16*)(G + 44040192);        // 16,777,216 -> ends 60,817,408
    float* ps0  = (float*)(G + 23068672);      // FFN2 split-K partials (khb..p dead)

    pe_kernel<<<2048, 256, 0, stream>>>(pe);
    f2h_kernel<<<49152, 256, 0, stream>>>(q_raw, q_h, 12582912);
    tconv_kernel<1><<<dim3(24, 24, 4), 256, 0, stream>>>(exp_w1, w1t, 768, 768);
    tconv_kernel<1><<<dim3(16, 24, 4), 256, 0, stream>>>(exp_w2, w2t, 768, 512);
    tconv_kernel<1><<<dim3(16, 96, 1), 256, 0, stream>>>(adapt_w, adaptt, 3072, 512);

    // ---- adapter summary in fp16 MFMA (split-K=2), gate, sparse fp32 fixup ----
    gemm_lp<1><<<dim3(4, 32, 2), 256, 0, stream>>>(
        q_h, 3072, 1536L, adaptt, 3072, 1536L, nullptr, 0,
        psum, nullptr, 512, 2097152L, 1536, 0, 0);
    gate_kernel<<<4096, 64, 0, stream>>>(psum, adapt_b, m_seq, gate_w, gate_b, gates, flags);
    fixup_kernel<<<4096, 64, 0, stream>>>(flags, q_raw, adapt_w, adapt_b,
                                          m_seq, gate_w, gate_b, gates);

    // ---- experts in fp16 (2 x z=2; h1 region aliases dead psum) ----
    for (int g = 0; g < 2; ++g) {
        gemm_lp<1><<<dim3(6, 32, 2), 256, 0, stream>>>(
            q_h + g * 1536, 3072, 768L, w1t + (size_t)g * 1179648, 768, 589824L,
            exp_b1 + g * 1536, 768, nullptr, h1b2, 768, 3145728L, 768, 1, 0);
        gemm_lp<1><<<dim3(4, 32, 2), 256, 0, stream>>>(
            h1b2, 768, 3145728L, w2t + (size_t)g * 786432, 768, 393216L,
            exp_b2 + g * 1024, 512, nullptr, expb + g * 1024, 2048, 512L, 768, 0, 0);
    }
    moe_ln_kernel<<<4096, 64, 0, stream>>>(expb, gates, moe_g, moe_b, pe, x, xb);
    y_kernel<<<8192, 256, 0, stream>>>(qa, pe, yb);

    // ---- layer weight conversions (bf16) ----
    tconv_kernel<0><<<dim3(16, 16, 4), 256, 0, stream>>>(kw, kwt, 512, 512);
    tconv_kernel<0><<<dim3(16, 16, 4), 256, 0, stream>>>(vw, vwt, 512, 512);
    tconv_kernel<0><<<dim3(16, 16, 4), 256, 0, stream>>>(ow, owt, 512, 512);
    tconv_kernel<0><<<dim3(64, 16, 4), 256, 0, stream>>>(fw1, fw1t, 512, 2048);
    tconv_kernel<0><<<dim3(16, 64, 4), 256, 0, stream>>>(fw2, fw2t, 2048, 512);

    // ---- transformer layers ----
    for (int i = 0; i < 4; ++i) {
        gemm_lp<0><<<dim3(4, 32), 256, 0, stream>>>(
            xb, 512, 0L, kwt + (size_t)i * 262144, 512, 0L, kb + i * 512, 0,
            nullptr, khb, 512, 0L, 512, 0, 0);
        gemm_lp<0><<<dim3(4, 32), 256, 0, stream>>>(
            yb, 512, 0L, vwt + (size_t)i * 262144, 512, 0L, vb + i * 512, 0,
            nullptr, vhT, 512, 0L, 512, 0, 1);
        attn_kernel<<<dim3(4, 8, 16), 256, 0, stream>>>(khb, vhT, ctxb);
        gemm_lp<0><<<dim3(4, 32), 256, 0, stream>>>(
            ctxb, 512, 0L, owt + (size_t)i * 262144, 512, 0L, ob + i * 512, 0,
            p, nullptr, 512, 0L, 512, 0, 0);
        add_ln_kernel<<<4096, 64, 0, stream>>>(
            x, xb, p, nullptr, nullptr, ln1g + i * 512, ln1b + i * 512, nullptr);
        gemm_lp<0><<<dim3(16, 32), 256, 0, stream>>>(
            xb, 512, 0L, fw1t + (size_t)i * 1048576, 512, 0L, fb1 + i * 2048, 0,
            nullptr, ffhb, 2048, 0L, 512, 1, 0);
        gemm_lp<0><<<dim3(4, 32, 2), 256, 0, stream>>>(
            ffhb, 2048, 1024L, fw2t + (size_t)i * 1048576, 2048, 1024L, nullptr, 0,
            ps0, nullptr, 512, 2097152L, 1024, 0, 0);
        add_ln_kernel<<<4096, 64, 0, stream>>>(
            x, xb, ps0, ps0 + 2097152, fb2 + i * 512,
            ln2g + i * 512, ln2b + i * 512, (i == 3) ? out : nullptr);
    }
}

// Round 10
// 1242.347 us; speedup vs baseline: 1.0529x; 1.0529x over previous
//
#include <hip/hip_runtime.h>
#include <hip/hip_bf16.h>
#include <hip/hip_fp16.h>

typedef unsigned short u16;
typedef __attribute__((ext_vector_type(8))) short short8;
typedef __attribute__((ext_vector_type(8))) _Float16 half8;
typedef __attribute__((ext_vector_type(4))) float floatx4;

__device__ __forceinline__ float bf2f(u16 u) {
    unsigned x = (unsigned)u << 16;
    return __uint_as_float(x);
}
__device__ __forceinline__ u16 f2bf(float f) {   // RNE
    unsigned x = __float_as_uint(f);
    unsigned r = (x + 0x7fffu + ((x >> 16) & 1u)) >> 16;
    return (u16)r;
}
__device__ __forceinline__ u16 f2h(float f) {
    __half h = __float2half(f);
    return __half_as_ushort(h);
}
__device__ __forceinline__ float h2f(u16 u) {
    return __half2float(__ushort_as_half(u));
}

__device__ __forceinline__ float wave_sum(float v) {
    #pragma unroll
    for (int off = 32; off; off >>= 1) v += __shfl_xor(v, off);
    return v;
}

// async global->LDS, 16B/lane; LDS base wave-uniform (HW adds lane*16)
__device__ __forceinline__ void async16(const u16* g, const u16* lds) {
    __builtin_amdgcn_global_load_lds(
        (const __attribute__((address_space(1))) void*)g,
        (__attribute__((address_space(3))) void*)lds, 16, 0, 0);
}

// ---------------------------------------------------------------------------
// Low-precision MFMA GEMM (DT=0 bf16, DT=1 fp16), z-batched.
// ---------------------------------------------------------------------------
template <int DT>
__global__ __launch_bounds__(256) void gemm_lp(
    const u16* __restrict__ A, int lda, long strideAz,
    const u16* __restrict__ Bt, int ldb, long strideBz,
    const float* __restrict__ bias, int strideBiasZ,
    float* __restrict__ Cf, u16* __restrict__ Cb, int ldc, long strideCz,
    int K, int act, int transC)
{
    __shared__ __align__(16) u16 Asm[128 * 32];
    __shared__ __align__(16) u16 Bsm[128 * 32];

    A += (size_t)blockIdx.z * strideAz;
    Bt += (size_t)blockIdx.z * strideBz;
    if (bias) bias += (size_t)blockIdx.z * strideBiasZ;
    if (Cf) Cf += (size_t)blockIdx.z * strideCz;
    if (Cb) Cb += (size_t)blockIdx.z * strideCz;

    const int tid = threadIdx.x;
    const int lane = tid & 63;
    const int wave = tid >> 6;
    const int m0 = blockIdx.y * 128, n0 = blockIdx.x * 128;
    const int wm = (wave >> 1) * 64, wn = (wave & 1) * 64;

    const int r0 = tid >> 2;
    const int kc = (tid & 3) * 8;
    const int kq = (lane >> 4) * 8;
    const int fm = lane & 15;

    const floatx4 zz = {0.f, 0.f, 0.f, 0.f};
    floatx4 acc[4][4];
    #pragma unroll
    for (int mt = 0; mt < 4; ++mt)
        #pragma unroll
        for (int nt = 0; nt < 4; ++nt) acc[mt][nt] = zz;

    const u16* ldsA0 = Asm + wave * 512;
    const u16* ldsA1 = Asm + 2048 + wave * 512;
    const u16* ldsB0 = Bsm + wave * 512;
    const u16* ldsB1 = Bsm + 2048 + wave * 512;

    for (int kt = 0; kt < K; kt += 32) {
        async16(&A[(size_t)(m0 + r0) * lda + kt + kc],      ldsA0);
        async16(&A[(size_t)(m0 + r0 + 64) * lda + kt + kc], ldsA1);
        async16(&Bt[(size_t)(n0 + r0) * ldb + kt + kc],      ldsB0);
        async16(&Bt[(size_t)(n0 + r0 + 64) * ldb + kt + kc], ldsB1);
        __syncthreads();

        #pragma unroll
        for (int mt = 0; mt < 4; ++mt) {
            #pragma unroll
            for (int nt = 0; nt < 4; ++nt) {
                if constexpr (DT == 0) {
                    short8 af = *(const short8*)&Asm[(wm + mt * 16 + fm) * 32 + kq];
                    short8 bf = *(const short8*)&Bsm[(wn + nt * 16 + fm) * 32 + kq];
                    acc[mt][nt] = __builtin_amdgcn_mfma_f32_16x16x32_bf16(af, bf, acc[mt][nt], 0, 0, 0);
                } else {
                    half8 af = *(const half8*)&Asm[(wm + mt * 16 + fm) * 32 + kq];
                    half8 bf = *(const half8*)&Bsm[(wn + nt * 16 + fm) * 32 + kq];
                    acc[mt][nt] = __builtin_amdgcn_mfma_f32_16x16x32_f16(af, bf, acc[mt][nt], 0, 0, 0);
                }
            }
        }
        __syncthreads();
    }

    const int cr = (lane >> 4) * 4;
    #pragma unroll
    for (int mt = 0; mt < 4; ++mt) {
        #pragma unroll
        for (int nt = 0; nt < 4; ++nt) {
            const int col = n0 + wn + nt * 16 + fm;
            const float bz = bias ? bias[col] : 0.f;
            #pragma unroll
            for (int r = 0; r < 4; ++r) {
                const int row = m0 + wm + mt * 16 + cr + r;
                float v = acc[mt][nt][r] + bz;
                if (act) v = fmaxf(v, 0.f);
                if (Cf) Cf[(size_t)row * ldc + col] = v;
                if (Cb) {
                    u16 ov = (DT == 0) ? f2bf(v) : f2h(v);
                    if (transC)
                        Cb[(((size_t)(row >> 10) * 512 + col) << 10) + (row & 1023)] = ov;
                    else
                        Cb[(size_t)row * ldc + col] = ov;
                }
            }
        }
    }
}

// ---------------------------------------------------------------------------
template <int DT>
__global__ __launch_bounds__(256) void tconv_kernel(
    const float* __restrict__ in, u16* __restrict__ out, int K, int N)
{
    __shared__ float t[32][33];
    const int n0 = blockIdx.x * 32, k0 = blockIdx.y * 32;
    const size_t bo = (size_t)blockIdx.z * K * N;
    const int tx = threadIdx.x & 31, ty = threadIdx.x >> 5;
    const float* src = in + bo;
    u16* dst = out + bo;
    #pragma unroll
    for (int r = ty; r < 32; r += 8) t[r][tx] = src[(size_t)(k0 + r) * N + n0 + tx];
    __syncthreads();
    #pragma unroll
    for (int r = ty; r < 32; r += 8) {
        float v = t[tx][r];
        dst[(size_t)(n0 + r) * K + k0 + tx] = (DT == 0) ? f2bf(v) : f2h(v);
    }
}

__global__ void f2h_kernel(const float* __restrict__ in, u16* __restrict__ out, int n)
{
    int i = blockIdx.x * 256 + threadIdx.x;
    if (i < n) out[i] = f2h(in[i]);
}

// ---------------------------------------------------------------------------
__global__ void pe_kernel(float* __restrict__ pe)
{
    int idx = blockIdx.x * 256 + threadIdx.x;
    int s = idx >> 9, d = idx & 511;
    float div = expf((float)(d & ~1) * (-9.210340371976184f / 512.0f));
    float ang = (float)s * div;
    pe[idx] = (d & 1) ? cosf(ang) : sinf(ang);
}

__global__ void y_kernel(const float* __restrict__ qa, const float* __restrict__ pe,
                         u16* __restrict__ yb)
{
    int idx = blockIdx.x * 256 + threadIdx.x;
    yb[idx] = f2bf(qa[idx] + pe[idx & 524287]);
}

// ---------------------------------------------------------------------------
// Gate from fp16-GEMM partials; flags rows with top2-top3 gap < TAU.
// ---------------------------------------------------------------------------
#define GATE_TAU 4e-3f
__global__ __launch_bounds__(64) void gate_kernel(
    const float* __restrict__ ps, const float* __restrict__ ab,
    const float* __restrict__ m_seq,
    const float* __restrict__ gw, const float* __restrict__ gb,
    float* __restrict__ gates, int* __restrict__ flags)
{
    const int r = blockIdx.x, t = threadIdx.x;
    float p0 = 0.f, p1 = 0.f, p2 = 0.f, p3 = 0.f;
    const float* s0 = ps + (size_t)r * 512;
    const float* s1 = ps + 2097152 + (size_t)r * 512;
    for (int j = t; j < 512; j += 64) {
        float s = fmaxf(s0[j] + s1[j] + ab[j], 0.f);
        const float* g = gw + (size_t)j * 4;
        p0 += s * g[0]; p1 += s * g[1]; p2 += s * g[2]; p3 += s * g[3];
    }
    {
        float m = m_seq[(size_t)r * 64 + t];
        const float* g = gw + (size_t)(512 + t) * 4;
        p0 += m * g[0]; p1 += m * g[1]; p2 += m * g[2]; p3 += m * g[3];
    }
    p0 = wave_sum(p0); p1 = wave_sum(p1); p2 = wave_sum(p2); p3 = wave_sum(p3);
    if (t == 0) {
        float lg[4] = { p0 + gb[0], p1 + gb[1], p2 + gb[2], p3 + gb[3] };
        float m1 = -INFINITY, m2 = -INFINITY, m3 = -INFINITY;
        #pragma unroll
        for (int k = 0; k < 4; ++k) {
            float v = lg[k];
            if (v > m1) { m3 = m2; m2 = m1; m1 = v; }
            else if (v > m2) { m3 = m2; m2 = v; }
            else if (v > m3) { m3 = v; }
        }
        flags[r] = (m2 - m3 < GATE_TAU) ? 1 : 0;
        float wv[4], s = 0.f;
        #pragma unroll
        for (int k = 0; k < 4; ++k) {
            wv[k] = (lg[k] >= m2) ? __expf(lg[k] - m1) : 0.f;
            s += wv[k];
        }
        float inv = 1.f / s;
        #pragma unroll
        for (int k = 0; k < 4; ++k) gates[(size_t)r * 4 + k] = wv[k] * inv;
    }
}

// ---------------------------------------------------------------------------
// fp32 gate fixup for flagged rows — parallel version (R9's was 1-wave serial,
// 191 us latency-bound). 256 thr: q row in LDS; 4 waves split K (768 each);
// lane covers 8 cols; LDS partial reduce; wave0 finishes logits+softmax.
// ---------------------------------------------------------------------------
__global__ __launch_bounds__(256) void fixup_kernel(
    const int* __restrict__ flags,
    const float* __restrict__ q_raw, const float* __restrict__ aw,
    const float* __restrict__ ab, const float* __restrict__ m_seq,
    const float* __restrict__ gw, const float* __restrict__ gb,
    float* __restrict__ gates)
{
    const int r = blockIdx.x;
    if (!flags[r]) return;
    __shared__ float qs[3072];
    __shared__ float ps[4][512];
    const int tid = threadIdx.x;
    const float* q = q_raw + (size_t)r * 3072;
    #pragma unroll
    for (int c = 0; c < 3; ++c)
        *(float4*)&qs[tid * 4 + c * 1024] = *(const float4*)&q[tid * 4 + c * 1024];
    __syncthreads();

    const int wave = tid >> 6, lane = tid & 63;
    float s[8] = {};
    const int k0 = wave * 768;
    for (int k = k0; k < k0 + 768; ++k) {
        const float qk = qs[k];
        const float* w = aw + (size_t)k * 512 + lane;
        #pragma unroll
        for (int c = 0; c < 8; ++c) s[c] += qk * w[c * 64];
    }
    #pragma unroll
    for (int c = 0; c < 8; ++c) ps[wave][lane + c * 64] = s[c];
    __syncthreads();

    if (wave == 0) {
        float p0 = 0.f, p1 = 0.f, p2 = 0.f, p3 = 0.f;
        #pragma unroll
        for (int c = 0; c < 8; ++c) {
            const int j = lane + c * 64;
            float sv = fmaxf(ps[0][j] + ps[1][j] + ps[2][j] + ps[3][j] + ab[j], 0.f);
            const float* g = gw + (size_t)j * 4;
            p0 += sv * g[0]; p1 += sv * g[1]; p2 += sv * g[2]; p3 += sv * g[3];
        }
        {
            float m = m_seq[(size_t)r * 64 + lane];
            const float* g = gw + (size_t)(512 + lane) * 4;
            p0 += m * g[0]; p1 += m * g[1]; p2 += m * g[2]; p3 += m * g[3];
        }
        p0 = wave_sum(p0); p1 = wave_sum(p1); p2 = wave_sum(p2); p3 = wave_sum(p3);
        if (lane == 0) {
            float lg[4] = { p0 + gb[0], p1 + gb[1], p2 + gb[2], p3 + gb[3] };
            float m1 = -INFINITY, m2 = -INFINITY;
            #pragma unroll
            for (int k = 0; k < 4; ++k) {
                float v = lg[k];
                if (v > m1) { m2 = m1; m1 = v; }
                else if (v > m2) { m2 = v; }
            }
            float wv[4], ssum = 0.f;
            #pragma unroll
            for (int k = 0; k < 4; ++k) {
                wv[k] = (lg[k] >= m2) ? __expf(lg[k] - m1) : 0.f;
                ssum += wv[k];
            }
            float inv = 1.f / ssum;
            #pragma unroll
            for (int k = 0; k < 4; ++k) gates[(size_t)r * 4 + k] = wv[k] * inv;
        }
    }
}

// ---------------------------------------------------------------------------
__global__ __launch_bounds__(64) void moe_ln_kernel(
    const u16* __restrict__ experts, const float* __restrict__ gates,
    const float* __restrict__ g, const float* __restrict__ bb,
    const float* __restrict__ pe, float* __restrict__ x, u16* __restrict__ xb)
{
    const int r = blockIdx.x, t = threadIdx.x;
    const u16* e = experts + (size_t)r * 2048;
    const float g0 = gates[r * 4 + 0], g1 = gates[r * 4 + 1];
    const float g2 = gates[r * 4 + 2], g3 = gates[r * 4 + 3];
    float v[8];
    #pragma unroll
    for (int it = 0; it < 8; ++it) {
        int d = t + it * 64;
        v[it] = g0 * h2f(e[d]) + g1 * h2f(e[512 + d])
              + g2 * h2f(e[1024 + d]) + g3 * h2f(e[1536 + d]);
    }
    float s = 0.f;
    #pragma unroll
    for (int it = 0; it < 8; ++it) s += v[it];
    s = wave_sum(s);
    const float mu = s * (1.f / 512.f);
    float q = 0.f;
    #pragma unroll
    for (int it = 0; it < 8; ++it) { float dd = v[it] - mu; q += dd * dd; }
    q = wave_sum(q);
    const float rstd = rsqrtf(q * (1.f / 512.f) + 1e-5f);
    const float* per = pe + (size_t)(r & 1023) * 512;
    #pragma unroll
    for (int it = 0; it < 8; ++it) {
        int d = t + it * 64;
        float o = (v[it] - mu) * rstd * g[d] + bb[d] + per[d];
        x[(size_t)r * 512 + d] = o;
        xb[(size_t)r * 512 + d] = f2bf(o);
    }
}

__global__ __launch_bounds__(64) void add_ln_kernel(
    float* __restrict__ x, u16* __restrict__ xb,
    const float* __restrict__ t0, const float* __restrict__ t1,
    const float* __restrict__ bias,
    const float* __restrict__ g, const float* __restrict__ bb,
    float* __restrict__ out2)
{
    const int r = blockIdx.x, t = threadIdx.x;
    float* xr = x + (size_t)r * 512;
    float v[8];
    #pragma unroll
    for (int it = 0; it < 8; ++it) {
        int d = t + it * 64;
        float tv = t0[(size_t)r * 512 + d];
        if (t1) tv += t1[(size_t)r * 512 + d];
        if (bias) tv += bias[d];
        v[it] = xr[d] + tv;
    }
    float s = 0.f;
    #pragma unroll
    for (int it = 0; it < 8; ++it) s += v[it];
    s = wave_sum(s);
    const float mu = s * (1.f / 512.f);
    float q = 0.f;
    #pragma unroll
    for (int it = 0; it < 8; ++it) { float dd = v[it] - mu; q += dd * dd; }
    q = wave_sum(q);
    const float rstd = rsqrtf(q * (1.f / 512.f) + 1e-5f);
    #pragma unroll
    for (int it = 0; it < 8; ++it) {
        int d = t + it * 64;
        float o = (v[it] - mu) * rstd * g[d] + bb[d];
        xr[d] = o;
        xb[(size_t)r * 512 + d] = f2bf(o);
        if (out2) out2[(size_t)r * 512 + d] = o;
    }
}

// ---------------------------------------------------------------------------
// MFMA flash strict-causal attention (bf16). V pre-transposed in global.
// ---------------------------------------------------------------------------
__global__ __launch_bounds__(256) void attn_kernel(
    const u16* __restrict__ kh, const u16* __restrict__ vhT,
    u16* __restrict__ ctx)
{
    __shared__ __align__(16) u16 Qs[64 * 64];
    __shared__ __align__(16) u16 Ks[64 * 64];
    __shared__ __align__(16) u16 Vt[64 * 72];
    __shared__ __align__(16) u16 Ps[64 * 72];

    const int tid = threadIdx.x;
    const int lane = tid & 63, wave = tid >> 6;
    const int quad = lane >> 4, fm = lane & 15;
    const int b = blockIdx.x, h = blockIdx.y;
    const int bz = blockIdx.z;
    const int it = (bz < 8) ? bz : (23 - bz);

    const u16* khb = kh + ((size_t)b * 1024) * 512 + h * 64;
    const u16* vtb = vhT + ((size_t)(b * 512 + h * 64)) * 1024;

    const int lj = tid >> 2;
    const int lc = tid & 3;

    {
        const u16* src = khb + (size_t)(it * 64 + lj) * 512 + lc * 16;
        *(uint4*)&Qs[lj * 64 + lc * 16]     = *(const uint4*)src;
        *(uint4*)&Qs[lj * 64 + lc * 16 + 8] = *(const uint4*)(src + 8);
    }

    const floatx4 zz = {0.f, 0.f, 0.f, 0.f};
    floatx4 o_acc[4];
    #pragma unroll
    for (int nt = 0; nt < 4; ++nt) o_acc[nt] = zz;
    float m_run[4] = { -INFINITY, -INFINITY, -INFINITY, -INFINITY };
    float l_run[4] = {};

    __syncthreads();

    for (int jt = 0; jt <= it; ++jt) {
        {
            const u16* ksrc = khb + (size_t)(jt * 64 + lj) * 512 + lc * 16;
            *(uint4*)&Ks[lj * 64 + lc * 16]     = *(const uint4*)ksrc;
            *(uint4*)&Ks[lj * 64 + lc * 16 + 8] = *(const uint4*)(ksrc + 8);
            const u16* vsrc = vtb + (size_t)lj * 1024 + jt * 64 + lc * 16;
            *(uint4*)&Vt[lj * 72 + lc * 16]     = *(const uint4*)vsrc;
            *(uint4*)&Vt[lj * 72 + lc * 16 + 8] = *(const uint4*)(vsrc + 8);
        }
        __syncthreads();

        floatx4 s_acc[4];
        #pragma unroll
        for (int nt = 0; nt < 4; ++nt) s_acc[nt] = zz;
        #pragma unroll
        for (int ks = 0; ks < 2; ++ks) {
            short8 af = *(const short8*)&Qs[(wave * 16 + fm) * 64 + ks * 32 + quad * 8];
            #pragma unroll
            for (int nt = 0; nt < 4; ++nt) {
                short8 bf = *(const short8*)&Ks[(nt * 16 + fm) * 64 + ks * 32 + quad * 8];
                s_acc[nt] = __builtin_amdgcn_mfma_f32_16x16x32_bf16(af, bf, s_acc[nt], 0, 0, 0);
            }
        }

        const bool diag = (jt == it);
        #pragma unroll
        for (int r = 0; r < 4; ++r) {
            const int rowi = wave * 16 + quad * 4 + r;
            float sv[4];
            #pragma unroll
            for (int nt = 0; nt < 4; ++nt) {
                float s = s_acc[nt][r] * 0.125f;
                if (diag && (nt * 16 + fm) >= rowi) s = -INFINITY;
                sv[nt] = s;
            }
            float mx = fmaxf(fmaxf(sv[0], sv[1]), fmaxf(sv[2], sv[3]));
            #pragma unroll
            for (int off = 1; off < 16; off <<= 1) mx = fmaxf(mx, __shfl_xor(mx, off));
            const float mn = fmaxf(m_run[r], mx);
            const float mfix = (mn == -INFINITY) ? 0.f : mn;
            const float alpha = (m_run[r] == -INFINITY) ? 0.f : __expf(m_run[r] - mn);
            m_run[r] = mn;
            float rs = 0.f;
            #pragma unroll
            for (int nt = 0; nt < 4; ++nt) {
                float p = __expf(sv[nt] - mfix);
                Ps[rowi * 72 + nt * 16 + fm] = f2bf(p);
                rs += p;
            }
            #pragma unroll
            for (int off = 1; off < 16; off <<= 1) rs += __shfl_xor(rs, off);
            l_run[r] = l_run[r] * alpha + rs;
            #pragma unroll
            for (int nt = 0; nt < 4; ++nt) o_acc[nt][r] *= alpha;
        }
        __syncthreads();

        #pragma unroll
        for (int ks = 0; ks < 2; ++ks) {
            short8 af = *(const short8*)&Ps[(wave * 16 + fm) * 72 + ks * 32 + quad * 8];
            #pragma unroll
            for (int nt = 0; nt < 4; ++nt) {
                short8 bf = *(const short8*)&Vt[(nt * 16 + fm) * 72 + ks * 32 + quad * 8];
                o_acc[nt] = __builtin_amdgcn_mfma_f32_16x16x32_bf16(af, bf, o_acc[nt], 0, 0, 0);
            }
        }
        __syncthreads();
    }

    u16* cb = ctx + ((size_t)b * 1024 + (size_t)it * 64 + wave * 16) * 512 + h * 64;
    #pragma unroll
    for (int r = 0; r < 4; ++r) {
        const int row = quad * 4 + r;
        const float inv = (l_run[r] > 0.f) ? 1.f / l_run[r] : 0.f;
        #pragma unroll
        for (int nt = 0; nt < 4; ++nt)
            cb[(size_t)row * 512 + nt * 16 + fm] = f2bf(o_acc[nt][r] * inv);
    }
}

// ---------------------------------------------------------------------------
extern "C" void kernel_launch(void* const* d_in, const int* in_sizes, int n_in,
                              void* d_out, int out_size, void* d_ws, size_t ws_size,
                              hipStream_t stream)
{
    const float* q_raw   = (const float*)d_in[0];
    const float* m_seq   = (const float*)d_in[1];
    const float* qa      = (const float*)d_in[2];
    const float* exp_w1  = (const float*)d_in[3];
    const float* exp_b1  = (const float*)d_in[4];
    const float* exp_w2  = (const float*)d_in[5];
    const float* exp_b2  = (const float*)d_in[6];
    const float* adapt_w = (const float*)d_in[7];
    const float* adapt_b = (const float*)d_in[8];
    const float* gate_w  = (const float*)d_in[9];
    const float* gate_b  = (const float*)d_in[10];
    const float* moe_g   = (const float*)d_in[11];
    const float* moe_b   = (const float*)d_in[12];
    const float* kw      = (const float*)d_in[13];
    const float* kb      = (const float*)d_in[14];
    const float* vw      = (const float*)d_in[15];
    const float* vb      = (const float*)d_in[16];
    const float* ow      = (const float*)d_in[17];
    const float* ob      = (const float*)d_in[18];
    const float* ln1g    = (const float*)d_in[19];
    const float* ln1b    = (const float*)d_in[20];
    const float* fw1     = (const float*)d_in[21];
    const float* fb1     = (const float*)d_in[22];
    const float* fw2     = (const float*)d_in[23];
    const float* fb2     = (const float*)d_in[24];
    const float* ln2g    = (const float*)d_in[25];
    const float* ln2b    = (const float*)d_in[26];
    float* out = (float*)d_out;

    const size_t NEED = 86048768ull;
    if (ws_size < NEED) return;

    char* base = (char*)d_ws;
    float* x  = (float*)(base + 0);
    u16*  xb  = (u16*)(base + 8388608);
    u16*  yb  = (u16*)(base + 12582912);
    char* G = base + 16777216;
    // ---- MoE phase ----
    u16*   w1t    = (u16*)(G + 0);
    u16*   w2t    = (u16*)(G + 4718592);
    u16*   adaptt = (u16*)(G + 7864320);
    u16*   q_h    = (u16*)(G + 11010048);
    float* psum   = (float*)(G + 36175872);
    u16*   h1b2   = (u16*)(G + 36175872);
    float* pe     = (float*)(G + 52953088);
    float* gates  = (float*)(G + 55050240);
    int*   flags  = (int*)(G + 55115776);
    u16*   expb   = (u16*)(G + 55132160);
    // ---- layer phase ----
    u16*   kwt  = (u16*)(G + 0);
    u16*   vwt  = (u16*)(G + 2097152);
    u16*   owt  = (u16*)(G + 4194304);
    u16*   fw1t = (u16*)(G + 6291456);
    u16*   fw2t = (u16*)(G + 14680064);
    u16*   khb  = (u16*)(G + 23068672);
    u16*   vhT  = (u16*)(G + 27262976);
    u16*   ctxb = (u16*)(G + 31457280);
    float* p    = (float*)(G + 35651584);
    u16*   ffhb = (u16*)(G + 44040192);
    float* ps0  = (float*)(G + 23068672);

    pe_kernel<<<2048, 256, 0, stream>>>(pe);
    f2h_kernel<<<49152, 256, 0, stream>>>(q_raw, q_h, 12582912);
    tconv_kernel<1><<<dim3(24, 24, 4), 256, 0, stream>>>(exp_w1, w1t, 768, 768);
    tconv_kernel<1><<<dim3(16, 24, 4), 256, 0, stream>>>(exp_w2, w2t, 768, 512);
    tconv_kernel<1><<<dim3(16, 96, 1), 256, 0, stream>>>(adapt_w, adaptt, 3072, 512);

    // ---- adapter summary fp16 MFMA (split-K=2), gate, parallel fp32 fixup ----
    gemm_lp<1><<<dim3(4, 32, 2), 256, 0, stream>>>(
        q_h, 3072, 1536L, adaptt, 3072, 1536L, nullptr, 0,
        psum, nullptr, 512, 2097152L, 1536, 0, 0);
    gate_kernel<<<4096, 64, 0, stream>>>(psum, adapt_b, m_seq, gate_w, gate_b, gates, flags);
    fixup_kernel<<<4096, 256, 0, stream>>>(flags, q_raw, adapt_w, adapt_b,
                                           m_seq, gate_w, gate_b, gates);

    // ---- experts fp16 ----
    for (int g = 0; g < 2; ++g) {
        gemm_lp<1><<<dim3(6, 32, 2), 256, 0, stream>>>(
            q_h + g * 1536, 3072, 768L, w1t + (size_t)g * 1179648, 768, 589824L,
            exp_b1 + g * 1536, 768, nullptr, h1b2, 768, 3145728L, 768, 1, 0);
        gemm_lp<1><<<dim3(4, 32, 2), 256, 0, stream>>>(
            h1b2, 768, 3145728L, w2t + (size_t)g * 786432, 768, 393216L,
            exp_b2 + g * 1024, 512, nullptr, expb + g * 1024, 2048, 512L, 768, 0, 0);
    }
    moe_ln_kernel<<<4096, 64, 0, stream>>>(expb, gates, moe_g, moe_b, pe, x, xb);
    y_kernel<<<8192, 256, 0, stream>>>(qa, pe, yb);

    // ---- layer weight conversions (bf16) ----
    tconv_kernel<0><<<dim3(16, 16, 4), 256, 0, stream>>>(kw, kwt, 512, 512);
    tconv_kernel<0><<<dim3(16, 16, 4), 256, 0, stream>>>(vw, vwt, 512, 512);
    tconv_kernel<0><<<dim3(16, 16, 4), 256, 0, stream>>>(ow, owt, 512, 512);
    tconv_kernel<0><<<dim3(64, 16, 4), 256, 0, stream>>>(fw1, fw1t, 512, 2048);
    tconv_kernel<0><<<dim3(16, 64, 4), 256, 0, stream>>>(fw2, fw2t, 2048, 512);

    // ---- transformer layers ----
    for (int i = 0; i < 4; ++i) {
        gemm_lp<0><<<dim3(4, 32), 256, 0, stream>>>(
            xb, 512, 0L, kwt + (size_t)i * 262144, 512, 0L, kb + i * 512, 0,
            nullptr, khb, 512, 0L, 512, 0, 0);
        gemm_lp<0><<<dim3(4, 32), 256, 0, stream>>>(
            yb, 512, 0L, vwt + (size_t)i * 262144, 512, 0L, vb + i * 512, 0,
            nullptr, vhT, 512, 0L, 512, 0, 1);
        attn_kernel<<<dim3(4, 8, 16), 256, 0, stream>>>(khb, vhT, ctxb);
        gemm_lp<0><<<dim3(4, 32), 256, 0, stream>>>(
            ctxb, 512, 0L, owt + (size_t)i * 262144, 512, 0L, ob + i * 512, 0,
            p, nullptr, 512, 0L, 512, 0, 0);
        add_ln_kernel<<<4096, 64, 0, stream>>>(
            x, xb, p, nullptr, nullptr, ln1g + i * 512, ln1b + i * 512, nullptr);
        gemm_lp<0><<<dim3(16, 32), 256, 0, stream>>>(
            xb, 512, 0L, fw1t + (size_t)i * 1048576, 512, 0L, fb1 + i * 2048, 0,
            nullptr, ffhb, 2048, 0L, 512, 1, 0);
        gemm_lp<0><<<dim3(4, 32, 2), 256, 0, stream>>>(
            ffhb, 2048, 1024L, fw2t + (size_t)i * 1048576, 2048, 1024L, nullptr, 0,
            ps0, nullptr, 512, 2097152L, 1024, 0, 0);
        add_ln_kernel<<<4096, 64, 0, stream>>>(
            x, xb, ps0, ps0 + 2097152, fb2 + i * 512,
            ln2g + i * 512, ln2b + i * 512, (i == 3) ? out : nullptr);
    }
}